// Round 13
// baseline (157.705 us; speedup 1.0000x reference)
//
#include <hip/hip_runtime.h>
#include <hip/hip_fp16.h>
#include <math.h>

#define IMG   224
#define PLANE (IMG * IMG)
#define POOL1 110
#define NB    128

// ws layout: S[128*150] f32 | (pad) | w1p[270] u32 | pad | xi ushort4
#define WS_W1P_OFF  77824ull
#define WS_XI_OFF   81920ull
#define WS_XI_BYTES (128ull * PLANE * 8ull)
#define WS_NEED     (WS_XI_OFF + WS_XI_BYTES + 16ull)  // +16: x1 overread pad

typedef __attribute__((ext_vector_type(2))) _Float16 half2_t;
typedef __attribute__((ext_vector_type(8))) unsigned short ushort8;

// dot2: acc += a.x*b.x + a.y*b.y  (f16 inputs, f32 accumulate)
static __device__ __forceinline__ float fdot2f(unsigned int a, unsigned int b, float c) {
#if __has_builtin(__builtin_amdgcn_fdot2)
  return __builtin_amdgcn_fdot2(__builtin_bit_cast(half2_t, a),
                                __builtin_bit_cast(half2_t, b), c, false);
#else
  float a0 = __half2float(__ushort_as_half((unsigned short)(a & 0xffff)));
  float a1 = __half2float(__ushort_as_half((unsigned short)(a >> 16)));
  float b0 = __half2float(__ushort_as_half((unsigned short)(b & 0xffff)));
  float b1 = __half2float(__ushort_as_half((unsigned short)(b >> 16)));
  return fmaf(a1, b1, fmaf(a0, b0, c));
#endif
}

static __device__ __forceinline__ float h2f(unsigned short u) {
  return __half2float(__ushort_as_half(u));
}

// ---------------------------------------------------------------------------
// Fused fc head (was kernel k2), run redundantly per k3 block.
// Lane t: oc = t&15, i-residue = t>>4 (i = res, res+4, ... < 150).
// S[b*150+i] is group-uniform (broadcast); w2 loads per-lane. Reduce the 4
// residue-partials with 2 shfl_xor steps; lanes 0..15 stage br[oc] in LDS;
// lane 0 runs the tiny fc1/fc2/sigmoid head and broadcasts w via LDS.
// ---------------------------------------------------------------------------
static __device__ __forceinline__ void head_weights(
    const float* __restrict__ S, const float* __restrict__ w2,
    const float* __restrict__ b2, const float* __restrict__ f1w,
    const float* __restrict__ f1b, const float* __restrict__ f2w,
    const float* __restrict__ f2b, int b, int tid, bool write_out,
    float* __restrict__ out, float* __restrict__ wsh /* LDS[18] */)
{
  if (tid < 64) {
    const int oc = tid & 15, res = tid >> 4;
    float a = 0.0f;
    #pragma unroll 1
    for (int i = res; i < 150; i += 4)
      a = fmaf(w2[oc * 150 + i], S[b * 150 + i], a);
    a += __shfl_xor(a, 16, 64);
    a += __shfl_xor(a, 32, 64);
    if (tid < 16)
      wsh[2 + oc] = b2[oc] + a * (1.0f / (106.0f * 106.0f));
  }
  __syncthreads();
  if (tid == 0) {
    float br[16];
    #pragma unroll
    for (int oc = 0; oc < 16; ++oc) br[oc] = wsh[2 + oc];
    float h[8];
    #pragma unroll
    for (int j = 0; j < 8; ++j) {
      float t = f1b[j];
      #pragma unroll
      for (int oc = 0; oc < 16; ++oc) t = fmaf(br[oc], f1w[j * 16 + oc], t);
      h[j] = fmaxf(t, 0.0f);
    }
    #pragma unroll
    for (int k = 0; k < 2; ++k) {
      float t = f2b[k];
      #pragma unroll
      for (int j = 0; j < 8; ++j) t = fmaf(h[j], f2w[k * 8 + j], t);
      float w = 2.0f / (1.0f + expf(-t));
      wsh[k] = w;
      if (write_out) out[2 * b + k] = w;
    }
  }
  __syncthreads();
}

// ---------------------------------------------------------------------------
// k0w: block 0 packs conv1 weights into w1p; blocks 1..75 zero S.
// ---------------------------------------------------------------------------
__global__ __launch_bounds__(256) void k0w_pack(
    const float* __restrict__ w1, unsigned int* __restrict__ w1p,
    float* __restrict__ S)
{
  const int t = threadIdx.x;
  if (blockIdx.x == 0) {
    if (t >= 90) return;
    const int ky = t % 5, r = t / 5, oc = r % 6, c = r / 6;
    const float* w = w1 + ((oc * 3 + c) * 5 + ky) * 5;
    unsigned int* o = w1p + t * 3;
    o[0] = __builtin_bit_cast(unsigned int, __builtin_amdgcn_cvt_pkrtz(w[0], w[1]));
    o[1] = __builtin_bit_cast(unsigned int, __builtin_amdgcn_cvt_pkrtz(w[2], w[3]));
    o[2] = __builtin_bit_cast(unsigned int, w[4]);
  } else {
    S[(blockIdx.x - 1) * 256 + t] = 0.0f;   // 75*256 = 19200 = 128*150
  }
}

// ---------------------------------------------------------------------------
// Kernel 1: conv1(3->6,5x5) + maxpool2x2 + shifted-window sums into S
// + fused xi emission. This round: channel loop fully unrolled for
// cross-channel ILP (LDS reads of c+1 under c's dot2 chain).
// ---------------------------------------------------------------------------
__global__ __launch_bounds__(256) void k1_conv1(
    const float* __restrict__ x, const unsigned int* __restrict__ w1p,
    const float* __restrict__ b1, float* __restrict__ S,
    ushort4* __restrict__ xi, const int write_xi)
{
  const int tid = threadIdx.x;
  const int tile = blockIdx.x;          // 0..48
  const int b = blockIdx.y;
  const int t_y = tile / 7, t_x = tile % 7;
  const int P0y = t_y * 16, P0x = t_x * 16;
  const int ty = tid >> 4, tx = tid & 15;
  const int py = P0y + ty, px = P0x + tx;
  const bool xedge = (t_x == 0) || (t_x == 6);   // block-uniform

  __shared__ _Float16 in_t[3][36][40];  // fp16 staging
  __shared__ float rp[16][6][5];

  const int by = 2 * P0y, bx = 2 * P0x;
  #pragma unroll
  for (int dr = 0; dr < 3; ++dr) {
    const int row = ty + dr * 16;
    if (dr == 2 && row >= 36) continue;
    const int gy = min(by + row, IMG - 1);
    #pragma unroll
    for (int dc = 0; dc < 3; ++dc) {
      const int col = tx + dc * 16;
      if (dc == 2 && col >= 36) continue;
      const int gx = min(bx + col, IMG - 1);
      const float* src = x + ((size_t)(b * 3) * IMG + gy) * IMG + gx;
      #pragma unroll
      for (int c = 0; c < 3; ++c)
        in_t[c][row][col] = (_Float16)src[c * PLANE];
    }
  }
  __syncthreads();

  float acc[6][4];
  #pragma unroll
  for (int oc = 0; oc < 6; ++oc) {
    float bb = b1[oc];
    acc[oc][0] = bb; acc[oc][1] = bb; acc[oc][2] = bb; acc[oc][3] = bb;
  }
  unsigned int core_r0[3], core_r1[3];

  #pragma unroll
  for (int c = 0; c < 3; ++c) {
    const unsigned int* wc = w1p + c * 90;   // [(oc*5+ky)*3 + j]
    #pragma unroll
    for (int i = 0; i < 6; ++i) {
      const unsigned int* rowp =
          (const unsigned int*)&in_t[c][2 * ty + i][2 * tx];
      const unsigned int u0 = rowp[0], u1 = rowp[1], u2 = rowp[2];
      const unsigned int o1 = (u0 >> 16) | (u1 << 16);   // (v1,v2)
      const unsigned int o3 = (u1 >> 16) | (u2 << 16);   // (v3,v4)
      const float f4 = h2f((unsigned short)(u2 & 0xffff));
      const float f5 = h2f((unsigned short)(u2 >> 16));
      if (i == 0) { core_r0[c] = u0; }
      if (i == 1) { core_r1[c] = u0; }
      #pragma unroll
      for (int oc = 0; oc < 6; ++oc) {
        if (i <= 4) {
          const unsigned int* w = wc + (oc * 5 + i) * 3;
          const unsigned int w01 = w[0], w23 = w[1];
          const float w4 = __builtin_bit_cast(float, w[2]);
          acc[oc][0] = fdot2f(u0, w01, acc[oc][0]);
          acc[oc][0] = fdot2f(u1, w23, acc[oc][0]);
          acc[oc][0] = fmaf(f4, w4, acc[oc][0]);
          acc[oc][1] = fdot2f(o1, w01, acc[oc][1]);
          acc[oc][1] = fdot2f(o3, w23, acc[oc][1]);
          acc[oc][1] = fmaf(f5, w4, acc[oc][1]);
        }
        if (i >= 1) {
          const unsigned int* w = wc + (oc * 5 + (i - 1)) * 3;
          const unsigned int w01 = w[0], w23 = w[1];
          const float w4 = __builtin_bit_cast(float, w[2]);
          acc[oc][2] = fdot2f(u0, w01, acc[oc][2]);
          acc[oc][2] = fdot2f(u1, w23, acc[oc][2]);
          acc[oc][2] = fmaf(f4, w4, acc[oc][2]);
          acc[oc][3] = fdot2f(o1, w01, acc[oc][3]);
          acc[oc][3] = fdot2f(o3, w23, acc[oc][3]);
          acc[oc][3] = fmaf(f5, w4, acc[oc][3]);
        }
      }
    }
  }

  if (write_xi) {
    const int gy0 = by + 2 * ty, gx0 = bx + 2 * tx;
    ushort4* dst = xi + (size_t)b * PLANE + (size_t)gy0 * IMG + gx0;
    {
      uint4 pk;
      pk.x = (core_r0[0] & 0xffffu) | (core_r0[1] << 16);
      pk.y = (core_r0[2] & 0xffffu);
      pk.z = (core_r0[0] >> 16) | (core_r0[1] & 0xffff0000u);
      pk.w = (core_r0[2] >> 16);
      *(uint4*)dst = pk;
    }
    {
      uint4 pk;
      pk.x = (core_r1[0] & 0xffffu) | (core_r1[1] << 16);
      pk.y = (core_r1[2] & 0xffffu);
      pk.z = (core_r1[0] >> 16) | (core_r1[1] & 0xffff0000u);
      pk.w = (core_r1[2] >> 16);
      *(uint4*)(dst + IMG) = pk;
    }
  }

  const bool valid = (py < POOL1) && (px < POOL1);
  float z[6];
  #pragma unroll
  for (int oc = 0; oc < 6; ++oc) {
    float m = fmaxf(fmaxf(acc[oc][0], acc[oc][1]),
                    fmaxf(acc[oc][2], acc[oc][3]));
    z[oc] = valid ? m : 0.0f;
  }

  if (xedge) {
    #pragma unroll
    for (int oc = 0; oc < 6; ++oc) {
      #pragma unroll
      for (int kx = 0; kx < 5; ++kx) {
        float vv = (px >= kx && px <= 105 + kx) ? z[oc] : 0.0f;
        vv += __shfl_xor(vv, 1, 16);
        vv += __shfl_xor(vv, 2, 16);
        vv += __shfl_xor(vv, 4, 16);
        vv += __shfl_xor(vv, 8, 16);
        if (tx == 0) rp[ty][oc][kx] = vv;
      }
    }
  } else {
    #pragma unroll
    for (int oc = 0; oc < 6; ++oc) {
      float vv = z[oc];
      vv += __shfl_xor(vv, 1, 16);
      vv += __shfl_xor(vv, 2, 16);
      vv += __shfl_xor(vv, 4, 16);
      vv += __shfl_xor(vv, 8, 16);
      if (tx == 0) rp[ty][oc][0] = vv;
    }
  }
  __syncthreads();

  if (tid < 150) {
    int oc = tid / 25, r = tid % 25, ky = r / 5, kx = r % 5;
    const int kxi = xedge ? kx : 0;
    float s = 0.f;
    #pragma unroll
    for (int t = 0; t < 16; ++t) {
      int gpy = P0y + t;
      if (gpy >= ky && gpy <= 105 + ky) s += rp[t][oc][kxi];
    }
    atomicAdd(&S[b * 150 + tid], s);
  }
}

// ---------------------------------------------------------------------------
// Kernel 3 (fast): fused fc-head + polar-sector gather, 4 sectors per block.
// The head is recomputed per block (~500 cy) — removes the k2 dispatch and
// one inter-kernel gap from the critical path.
// ---------------------------------------------------------------------------
__global__ __launch_bounds__(320) void k3_sector(
    const ushort4* __restrict__ xi, const float* __restrict__ lprev,
    const float* __restrict__ g2d, const float* __restrict__ S,
    const float* __restrict__ w2, const float* __restrict__ b2,
    const float* __restrict__ f1w, const float* __restrict__ f1b,
    const float* __restrict__ f2w, const float* __restrict__ f2b,
    float* __restrict__ out)
{
  const int sgrp = blockIdx.x;  // 0..7  -> sectors 4*sgrp .. 4*sgrp+3
  const int b = blockIdx.y;     // 0..127
  const int tid = threadIdx.x;  // 0..319
  const int cc = tid % 10;      // theta col within sector
  const int chunk = tid / 10;   // 0..31 -> rows 5*chunk..5*chunk+4
  const int h = chunk >> 1;     // output radius bin

  __shared__ float part[16 * 3];
  __shared__ float wsh[18];     // [0,1]=weight, [2..17]=br staging

  if (tid < 48) part[tid] = 0.0f;
  head_weights(S, w2, b2, f1w, f1b, f2w, f2b, b, tid,
               /*write_out=*/sgrp == 0, out, wsh);
  // (head_weights ends with __syncthreads; part[] init is visible)

  const float lx = lprev[2 * b],  ly = lprev[2 * b + 1];
  const float wx = wsh[0],        wy = wsh[1];
  const float axx = 112.0f * wx, bxx = fmaf(lx, axx, 111.5f);
  const float ayy = 112.0f * wy, byy = fmaf(ly, ayy, 111.5f);
  const int r0 = chunk * 5;
  const unsigned short* xbs = (const unsigned short*)(xi + (size_t)b * PLANE);
  const float2* gp = (const float2*)g2d;

  #pragma unroll 1
  for (int q = 0; q < 4; ++q) {
    const int s = sgrp * 4 + q;
    const int col = s * 10 + cc;
    float a0 = 0.f, a1 = 0.f, a2 = 0.f;
    #pragma unroll
    for (int j = 0; j < 5; ++j) {
      const float2 g = gp[(r0 + j) * 320 + col];
      float ix = fminf(fmaxf(fmaf(g.x, axx, bxx), 0.0f), 223.0f);
      float iy = fminf(fmaxf(fmaf(g.y, ayy, byy), 0.0f), 223.0f);
      float x0f = floorf(ix), y0f = floorf(iy);
      float fx = ix - x0f, fy = iy - y0f;
      int x0 = (int)x0f, y0 = (int)y0f;
      int y1 = min(y0 + 1, IMG - 1);
      ushort8 t, u;                    // [pix x0: c0 c1 c2 pad | pix x0+1]
      __builtin_memcpy(&t, xbs + 4 * (y0 * IMG + x0), 16);
      __builtin_memcpy(&u, xbs + 4 * (y1 * IMG + x0), 16);
      float w00 = (1.f - fx) * (1.f - fy), w01 = fx * (1.f - fy);
      float w10 = (1.f - fx) * fy,         w11 = fx * fy;
      a0 += w00 * h2f(t[0]) + w01 * h2f(t[4]) + w10 * h2f(u[0]) + w11 * h2f(u[4]);
      a1 += w00 * h2f(t[1]) + w01 * h2f(t[5]) + w10 * h2f(u[1]) + w11 * h2f(u[5]);
      a2 += w00 * h2f(t[2]) + w01 * h2f(t[6]) + w10 * h2f(u[2]) + w11 * h2f(u[6]);
    }
    atomicAdd(&part[h * 3 + 0], a0);
    atomicAdd(&part[h * 3 + 1], a1);
    atomicAdd(&part[h * 3 + 2], a2);
    __syncthreads();
    if (tid < 48) {
      const int hh = tid / 3, c = tid - hh * 3;
      out[256 + (((b * 3 + c) * 16 + hh) * 32) + s] = part[tid] * 0.01f;
      part[tid] = 0.0f;
    }
    __syncthreads();
  }
}

// ---------------------------------------------------------------------------
// Kernel 3 (fallback, f32 planar) — used only if ws_size too small for xi.
// ---------------------------------------------------------------------------
__global__ __launch_bounds__(320) void k3_fallback(
    const float* __restrict__ x, const float* __restrict__ lprev,
    const float* __restrict__ g2d, const float* __restrict__ S,
    const float* __restrict__ w2, const float* __restrict__ b2,
    const float* __restrict__ f1w, const float* __restrict__ f1b,
    const float* __restrict__ f2w, const float* __restrict__ f2b,
    float* __restrict__ out)
{
  const int s = blockIdx.x;
  const int b = blockIdx.y;
  const int tid = threadIdx.x;
  const int cc = tid % 10;
  const int chunk = tid / 10;
  const int h = chunk >> 1;

  __shared__ float part[16 * 3];
  __shared__ float wsh[18];

  if (tid < 48) part[tid] = 0.0f;
  head_weights(S, w2, b2, f1w, f1b, f2w, f2b, b, tid,
               /*write_out=*/s == 0, out, wsh);

  const float lx = lprev[2 * b],  ly = lprev[2 * b + 1];
  const float wx = wsh[0],        wy = wsh[1];
  const int col = s * 10 + cc;
  const int r0 = chunk * 5;
  const float* xb = x + (size_t)b * 3 * PLANE;
  const float* p0 = xb;
  const float* p1 = xb + PLANE;
  const float* p2 = xb + 2 * PLANE;
  const float2* gp = (const float2*)g2d;

  float a0 = 0.f, a1 = 0.f, a2 = 0.f;
  #pragma unroll
  for (int j = 0; j < 5; ++j) {
    const int rr = r0 + j;
    const float2 g = gp[rr * 320 + col];
    float gx = (lx + g.x) * wx;
    float gy = (ly + g.y) * wy;
    float ix = ((gx + 1.0f) * 224.0f - 1.0f) * 0.5f;
    float iy = ((gy + 1.0f) * 224.0f - 1.0f) * 0.5f;
    ix = fminf(fmaxf(ix, 0.0f), 223.0f);
    iy = fminf(fmaxf(iy, 0.0f), 223.0f);
    float x0f = floorf(ix), y0f = floorf(iy);
    float fx = ix - x0f, fy = iy - y0f;
    int x0 = (int)x0f, y0 = (int)y0f;
    int x1 = min(x0 + 1, IMG - 1), y1 = min(y0 + 1, IMG - 1);
    float w00 = (1.f - fx) * (1.f - fy), w01 = fx * (1.f - fy);
    float w10 = (1.f - fx) * fy,         w11 = fx * fy;
    int o00 = y0 * IMG + x0, o01 = y0 * IMG + x1;
    int o10 = y1 * IMG + x0, o11 = y1 * IMG + x1;
    a0 += w00 * p0[o00] + w01 * p0[o01] + w10 * p0[o10] + w11 * p0[o11];
    a1 += w00 * p1[o00] + w01 * p1[o01] + w10 * p1[o10] + w11 * p1[o11];
    a2 += w00 * p2[o00] + w01 * p2[o01] + w10 * p2[o10] + w11 * p2[o11];
  }
  atomicAdd(&part[h * 3 + 0], a0);
  atomicAdd(&part[h * 3 + 1], a1);
  atomicAdd(&part[h * 3 + 2], a2);
  __syncthreads();

  if (tid < 48) {
    const int hh = tid / 3, c = tid - hh * 3;
    out[256 + (((b * 3 + c) * 16 + hh) * 32) + s] = part[tid] * 0.01f;
  }
}

// ---------------------------------------------------------------------------
extern "C" void kernel_launch(void* const* d_in, const int* in_sizes, int n_in,
                              void* d_out, int out_size, void* d_ws, size_t ws_size,
                              hipStream_t stream) {
  const float* x     = (const float*)d_in[0];
  const float* lprev = (const float*)d_in[1];
  const float* g2d   = (const float*)d_in[2];
  const float* w1    = (const float*)d_in[3];
  const float* b1    = (const float*)d_in[4];
  const float* w2    = (const float*)d_in[5];
  const float* b2    = (const float*)d_in[6];
  const float* f1w   = (const float*)d_in[7];
  const float* f1b   = (const float*)d_in[8];
  const float* f2w   = (const float*)d_in[9];
  const float* f2b   = (const float*)d_in[10];
  float* out = (float*)d_out;

  float* S   = (float*)d_ws;                      // [128][150]
  unsigned int* w1p = (unsigned int*)((char*)d_ws + WS_W1P_OFF);
  ushort4* xi = (ushort4*)((char*)d_ws + WS_XI_OFF);

  const bool fast = (ws_size >= WS_NEED);

  k0w_pack<<<76, 256, 0, stream>>>(w1, w1p, S);   // weights + S zeroing
  k1_conv1<<<dim3(49, NB), 256, 0, stream>>>(x, w1p, b1, S, xi, fast ? 1 : 0);
  if (fast)
    k3_sector<<<dim3(8, NB), 320, 0, stream>>>(
        xi, lprev, g2d, S, w2, b2, f1w, f1b, f2w, f2b, out);
  else
    k3_fallback<<<dim3(32, NB), 320, 0, stream>>>(
        x, lprev, g2d, S, w2, b2, f1w, f1b, f2w, f2b, out);
}

// Round 14
// 130.174 us; speedup vs baseline: 1.2115x; 1.2115x over previous
//
#include <hip/hip_runtime.h>
#include <hip/hip_fp16.h>
#include <math.h>

#define IMG   224
#define PLANE (IMG * IMG)
#define POOL1 110
#define NB    128

// ws layout: S[128*150] f32 | (pad) | w1p[270] u32 | pad | xi ushort4
#define WS_W1P_OFF  77824ull
#define WS_XI_OFF   81920ull
#define WS_XI_BYTES (128ull * PLANE * 8ull)
#define WS_NEED     (WS_XI_OFF + WS_XI_BYTES + 16ull)  // +16: x1 overread pad

typedef __attribute__((ext_vector_type(2))) _Float16 half2_t;
typedef __attribute__((ext_vector_type(8))) unsigned short ushort8;

// dot2: acc += a.x*b.x + a.y*b.y  (f16 inputs, f32 accumulate)
static __device__ __forceinline__ float fdot2f(unsigned int a, unsigned int b, float c) {
#if __has_builtin(__builtin_amdgcn_fdot2)
  return __builtin_amdgcn_fdot2(__builtin_bit_cast(half2_t, a),
                                __builtin_bit_cast(half2_t, b), c, false);
#else
  float a0 = __half2float(__ushort_as_half((unsigned short)(a & 0xffff)));
  float a1 = __half2float(__ushort_as_half((unsigned short)(a >> 16)));
  float b0 = __half2float(__ushort_as_half((unsigned short)(b & 0xffff)));
  float b1 = __half2float(__ushort_as_half((unsigned short)(b >> 16)));
  return fmaf(a1, b1, fmaf(a0, b0, c));
#endif
}

static __device__ __forceinline__ float h2f(unsigned short u) {
  return __half2float(__ushort_as_half(u));
}

// ---------------------------------------------------------------------------
// Fused fc head (was kernel k2), run redundantly per k3 block.
// ---------------------------------------------------------------------------
static __device__ __forceinline__ void head_weights(
    const float* __restrict__ S, const float* __restrict__ w2,
    const float* __restrict__ b2, const float* __restrict__ f1w,
    const float* __restrict__ f1b, const float* __restrict__ f2w,
    const float* __restrict__ f2b, int b, int tid, bool write_out,
    float* __restrict__ out, float* __restrict__ wsh /* LDS[18] */)
{
  if (tid < 64) {
    const int oc = tid & 15, res = tid >> 4;
    float a = 0.0f;
    #pragma unroll 1
    for (int i = res; i < 150; i += 4)
      a = fmaf(w2[oc * 150 + i], S[b * 150 + i], a);
    a += __shfl_xor(a, 16, 64);
    a += __shfl_xor(a, 32, 64);
    if (tid < 16)
      wsh[2 + oc] = b2[oc] + a * (1.0f / (106.0f * 106.0f));
  }
  __syncthreads();
  if (tid == 0) {
    float br[16];
    #pragma unroll
    for (int oc = 0; oc < 16; ++oc) br[oc] = wsh[2 + oc];
    float h[8];
    #pragma unroll
    for (int j = 0; j < 8; ++j) {
      float t = f1b[j];
      #pragma unroll
      for (int oc = 0; oc < 16; ++oc) t = fmaf(br[oc], f1w[j * 16 + oc], t);
      h[j] = fmaxf(t, 0.0f);
    }
    #pragma unroll
    for (int k = 0; k < 2; ++k) {
      float t = f2b[k];
      #pragma unroll
      for (int j = 0; j < 8; ++j) t = fmaf(h[j], f2w[k * 8 + j], t);
      float w = 2.0f / (1.0f + expf(-t));
      wsh[k] = w;
      if (write_out) out[2 * b + k] = w;
    }
  }
  __syncthreads();
}

// ---------------------------------------------------------------------------
// k0w: block 0 packs conv1 weights into w1p; blocks 1..75 zero S.
// ---------------------------------------------------------------------------
__global__ __launch_bounds__(256) void k0w_pack(
    const float* __restrict__ w1, unsigned int* __restrict__ w1p,
    float* __restrict__ S)
{
  const int t = threadIdx.x;
  if (blockIdx.x == 0) {
    if (t >= 90) return;
    const int ky = t % 5, r = t / 5, oc = r % 6, c = r / 6;
    const float* w = w1 + ((oc * 3 + c) * 5 + ky) * 5;
    unsigned int* o = w1p + t * 3;
    o[0] = __builtin_bit_cast(unsigned int, __builtin_amdgcn_cvt_pkrtz(w[0], w[1]));
    o[1] = __builtin_bit_cast(unsigned int, __builtin_amdgcn_cvt_pkrtz(w[2], w[3]));
    o[2] = __builtin_bit_cast(unsigned int, w[4]);
  } else {
    S[(blockIdx.x - 1) * 256 + t] = 0.0f;   // 75*256 = 19200 = 128*150
  }
}

// ---------------------------------------------------------------------------
// Kernel 1: conv1(3->6,5x5) + maxpool2x2 + shifted-window sums into S
// + fused xi emission. Channel loop at unroll-1 (R12's full unroll: VGPR
// 32->44, occupancy 63->48%, dur 90->118 — TLP loss beat the ILP gain).
// ---------------------------------------------------------------------------
__global__ __launch_bounds__(256) void k1_conv1(
    const float* __restrict__ x, const unsigned int* __restrict__ w1p,
    const float* __restrict__ b1, float* __restrict__ S,
    ushort4* __restrict__ xi, const int write_xi)
{
  const int tid = threadIdx.x;
  const int tile = blockIdx.x;          // 0..48
  const int b = blockIdx.y;
  const int t_y = tile / 7, t_x = tile % 7;
  const int P0y = t_y * 16, P0x = t_x * 16;
  const int ty = tid >> 4, tx = tid & 15;
  const int py = P0y + ty, px = P0x + tx;
  const bool xedge = (t_x == 0) || (t_x == 6);   // block-uniform

  __shared__ _Float16 in_t[3][36][40];  // fp16 staging
  __shared__ float rp[16][6][5];

  const int by = 2 * P0y, bx = 2 * P0x;
  #pragma unroll
  for (int dr = 0; dr < 3; ++dr) {
    const int row = ty + dr * 16;
    if (dr == 2 && row >= 36) continue;
    const int gy = min(by + row, IMG - 1);
    #pragma unroll
    for (int dc = 0; dc < 3; ++dc) {
      const int col = tx + dc * 16;
      if (dc == 2 && col >= 36) continue;
      const int gx = min(bx + col, IMG - 1);
      const float* src = x + ((size_t)(b * 3) * IMG + gy) * IMG + gx;
      #pragma unroll
      for (int c = 0; c < 3; ++c)
        in_t[c][row][col] = (_Float16)src[c * PLANE];
    }
  }
  __syncthreads();

  float acc[6][4];
  #pragma unroll
  for (int oc = 0; oc < 6; ++oc) {
    float bb = b1[oc];
    acc[oc][0] = bb; acc[oc][1] = bb; acc[oc][2] = bb; acc[oc][3] = bb;
  }
  unsigned int core_r0[3], core_r1[3];

  #pragma unroll 1
  for (int c = 0; c < 3; ++c) {
    const unsigned int* wc = w1p + c * 90;   // [(oc*5+ky)*3 + j]
    #pragma unroll
    for (int i = 0; i < 6; ++i) {
      const unsigned int* rowp =
          (const unsigned int*)&in_t[c][2 * ty + i][2 * tx];
      const unsigned int u0 = rowp[0], u1 = rowp[1], u2 = rowp[2];
      const unsigned int o1 = (u0 >> 16) | (u1 << 16);   // (v1,v2)
      const unsigned int o3 = (u1 >> 16) | (u2 << 16);   // (v3,v4)
      const float f4 = h2f((unsigned short)(u2 & 0xffff));
      const float f5 = h2f((unsigned short)(u2 >> 16));
      if (i == 0) { core_r0[c] = u0; }
      if (i == 1) { core_r1[c] = u0; }
      #pragma unroll
      for (int oc = 0; oc < 6; ++oc) {
        if (i <= 4) {
          const unsigned int* w = wc + (oc * 5 + i) * 3;
          const unsigned int w01 = w[0], w23 = w[1];
          const float w4 = __builtin_bit_cast(float, w[2]);
          acc[oc][0] = fdot2f(u0, w01, acc[oc][0]);
          acc[oc][0] = fdot2f(u1, w23, acc[oc][0]);
          acc[oc][0] = fmaf(f4, w4, acc[oc][0]);
          acc[oc][1] = fdot2f(o1, w01, acc[oc][1]);
          acc[oc][1] = fdot2f(o3, w23, acc[oc][1]);
          acc[oc][1] = fmaf(f5, w4, acc[oc][1]);
        }
        if (i >= 1) {
          const unsigned int* w = wc + (oc * 5 + (i - 1)) * 3;
          const unsigned int w01 = w[0], w23 = w[1];
          const float w4 = __builtin_bit_cast(float, w[2]);
          acc[oc][2] = fdot2f(u0, w01, acc[oc][2]);
          acc[oc][2] = fdot2f(u1, w23, acc[oc][2]);
          acc[oc][2] = fmaf(f4, w4, acc[oc][2]);
          acc[oc][3] = fdot2f(o1, w01, acc[oc][3]);
          acc[oc][3] = fdot2f(o3, w23, acc[oc][3]);
          acc[oc][3] = fmaf(f5, w4, acc[oc][3]);
        }
      }
    }
  }

  if (write_xi) {
    const int gy0 = by + 2 * ty, gx0 = bx + 2 * tx;
    ushort4* dst = xi + (size_t)b * PLANE + (size_t)gy0 * IMG + gx0;
    {
      uint4 pk;
      pk.x = (core_r0[0] & 0xffffu) | (core_r0[1] << 16);
      pk.y = (core_r0[2] & 0xffffu);
      pk.z = (core_r0[0] >> 16) | (core_r0[1] & 0xffff0000u);
      pk.w = (core_r0[2] >> 16);
      *(uint4*)dst = pk;
    }
    {
      uint4 pk;
      pk.x = (core_r1[0] & 0xffffu) | (core_r1[1] << 16);
      pk.y = (core_r1[2] & 0xffffu);
      pk.z = (core_r1[0] >> 16) | (core_r1[1] & 0xffff0000u);
      pk.w = (core_r1[2] >> 16);
      *(uint4*)(dst + IMG) = pk;
    }
  }

  const bool valid = (py < POOL1) && (px < POOL1);
  float z[6];
  #pragma unroll
  for (int oc = 0; oc < 6; ++oc) {
    float m = fmaxf(fmaxf(acc[oc][0], acc[oc][1]),
                    fmaxf(acc[oc][2], acc[oc][3]));
    z[oc] = valid ? m : 0.0f;
  }

  if (xedge) {
    #pragma unroll
    for (int oc = 0; oc < 6; ++oc) {
      #pragma unroll
      for (int kx = 0; kx < 5; ++kx) {
        float vv = (px >= kx && px <= 105 + kx) ? z[oc] : 0.0f;
        vv += __shfl_xor(vv, 1, 16);
        vv += __shfl_xor(vv, 2, 16);
        vv += __shfl_xor(vv, 4, 16);
        vv += __shfl_xor(vv, 8, 16);
        if (tx == 0) rp[ty][oc][kx] = vv;
      }
    }
  } else {
    #pragma unroll
    for (int oc = 0; oc < 6; ++oc) {
      float vv = z[oc];
      vv += __shfl_xor(vv, 1, 16);
      vv += __shfl_xor(vv, 2, 16);
      vv += __shfl_xor(vv, 4, 16);
      vv += __shfl_xor(vv, 8, 16);
      if (tx == 0) rp[ty][oc][0] = vv;
    }
  }
  __syncthreads();

  if (tid < 150) {
    int oc = tid / 25, r = tid % 25, ky = r / 5, kx = r % 5;
    const int kxi = xedge ? kx : 0;
    float s = 0.f;
    #pragma unroll
    for (int t = 0; t < 16; ++t) {
      int gpy = P0y + t;
      if (gpy >= ky && gpy <= 105 + ky) s += rp[t][oc][kxi];
    }
    atomicAdd(&S[b * 150 + tid], s);
  }
}

// ---------------------------------------------------------------------------
// Kernel 3 (fast): fused fc-head + polar-sector gather, 4 sectors per block.
// ---------------------------------------------------------------------------
__global__ __launch_bounds__(320) void k3_sector(
    const ushort4* __restrict__ xi, const float* __restrict__ lprev,
    const float* __restrict__ g2d, const float* __restrict__ S,
    const float* __restrict__ w2, const float* __restrict__ b2,
    const float* __restrict__ f1w, const float* __restrict__ f1b,
    const float* __restrict__ f2w, const float* __restrict__ f2b,
    float* __restrict__ out)
{
  const int sgrp = blockIdx.x;  // 0..7  -> sectors 4*sgrp .. 4*sgrp+3
  const int b = blockIdx.y;     // 0..127
  const int tid = threadIdx.x;  // 0..319
  const int cc = tid % 10;      // theta col within sector
  const int chunk = tid / 10;   // 0..31 -> rows 5*chunk..5*chunk+4
  const int h = chunk >> 1;     // output radius bin

  __shared__ float part[16 * 3];
  __shared__ float wsh[18];     // [0,1]=weight, [2..17]=br staging

  if (tid < 48) part[tid] = 0.0f;
  head_weights(S, w2, b2, f1w, f1b, f2w, f2b, b, tid,
               /*write_out=*/sgrp == 0, out, wsh);

  const float lx = lprev[2 * b],  ly = lprev[2 * b + 1];
  const float wx = wsh[0],        wy = wsh[1];
  const float axx = 112.0f * wx, bxx = fmaf(lx, axx, 111.5f);
  const float ayy = 112.0f * wy, byy = fmaf(ly, ayy, 111.5f);
  const int r0 = chunk * 5;
  const unsigned short* xbs = (const unsigned short*)(xi + (size_t)b * PLANE);
  const float2* gp = (const float2*)g2d;

  #pragma unroll 1
  for (int q = 0; q < 4; ++q) {
    const int s = sgrp * 4 + q;
    const int col = s * 10 + cc;
    float a0 = 0.f, a1 = 0.f, a2 = 0.f;
    #pragma unroll
    for (int j = 0; j < 5; ++j) {
      const float2 g = gp[(r0 + j) * 320 + col];
      float ix = fminf(fmaxf(fmaf(g.x, axx, bxx), 0.0f), 223.0f);
      float iy = fminf(fmaxf(fmaf(g.y, ayy, byy), 0.0f), 223.0f);
      float x0f = floorf(ix), y0f = floorf(iy);
      float fx = ix - x0f, fy = iy - y0f;
      int x0 = (int)x0f, y0 = (int)y0f;
      int y1 = min(y0 + 1, IMG - 1);
      ushort8 t, u;                    // [pix x0: c0 c1 c2 pad | pix x0+1]
      __builtin_memcpy(&t, xbs + 4 * (y0 * IMG + x0), 16);
      __builtin_memcpy(&u, xbs + 4 * (y1 * IMG + x0), 16);
      float w00 = (1.f - fx) * (1.f - fy), w01 = fx * (1.f - fy);
      float w10 = (1.f - fx) * fy,         w11 = fx * fy;
      a0 += w00 * h2f(t[0]) + w01 * h2f(t[4]) + w10 * h2f(u[0]) + w11 * h2f(u[4]);
      a1 += w00 * h2f(t[1]) + w01 * h2f(t[5]) + w10 * h2f(u[1]) + w11 * h2f(u[5]);
      a2 += w00 * h2f(t[2]) + w01 * h2f(t[6]) + w10 * h2f(u[2]) + w11 * h2f(u[6]);
    }
    atomicAdd(&part[h * 3 + 0], a0);
    atomicAdd(&part[h * 3 + 1], a1);
    atomicAdd(&part[h * 3 + 2], a2);
    __syncthreads();
    if (tid < 48) {
      const int hh = tid / 3, c = tid - hh * 3;
      out[256 + (((b * 3 + c) * 16 + hh) * 32) + s] = part[tid] * 0.01f;
      part[tid] = 0.0f;
    }
    __syncthreads();
  }
}

// ---------------------------------------------------------------------------
// Kernel 3 (fallback, f32 planar) — used only if ws_size too small for xi.
// ---------------------------------------------------------------------------
__global__ __launch_bounds__(320) void k3_fallback(
    const float* __restrict__ x, const float* __restrict__ lprev,
    const float* __restrict__ g2d, const float* __restrict__ S,
    const float* __restrict__ w2, const float* __restrict__ b2,
    const float* __restrict__ f1w, const float* __restrict__ f1b,
    const float* __restrict__ f2w, const float* __restrict__ f2b,
    float* __restrict__ out)
{
  const int s = blockIdx.x;
  const int b = blockIdx.y;
  const int tid = threadIdx.x;
  const int cc = tid % 10;
  const int chunk = tid / 10;
  const int h = chunk >> 1;

  __shared__ float part[16 * 3];
  __shared__ float wsh[18];

  if (tid < 48) part[tid] = 0.0f;
  head_weights(S, w2, b2, f1w, f1b, f2w, f2b, b, tid,
               /*write_out=*/s == 0, out, wsh);

  const float lx = lprev[2 * b],  ly = lprev[2 * b + 1];
  const float wx = wsh[0],        wy = wsh[1];
  const int col = s * 10 + cc;
  const int r0 = chunk * 5;
  const float* xb = x + (size_t)b * 3 * PLANE;
  const float* p0 = xb;
  const float* p1 = xb + PLANE;
  const float* p2 = xb + 2 * PLANE;
  const float2* gp = (const float2*)g2d;

  float a0 = 0.f, a1 = 0.f, a2 = 0.f;
  #pragma unroll
  for (int j = 0; j < 5; ++j) {
    const int rr = r0 + j;
    const float2 g = gp[rr * 320 + col];
    float gx = (lx + g.x) * wx;
    float gy = (ly + g.y) * wy;
    float ix = ((gx + 1.0f) * 224.0f - 1.0f) * 0.5f;
    float iy = ((gy + 1.0f) * 224.0f - 1.0f) * 0.5f;
    ix = fminf(fmaxf(ix, 0.0f), 223.0f);
    iy = fminf(fmaxf(iy, 0.0f), 223.0f);
    float x0f = floorf(ix), y0f = floorf(iy);
    float fx = ix - x0f, fy = iy - y0f;
    int x0 = (int)x0f, y0 = (int)y0f;
    int x1 = min(x0 + 1, IMG - 1), y1 = min(y0 + 1, IMG - 1);
    float w00 = (1.f - fx) * (1.f - fy), w01 = fx * (1.f - fy);
    float w10 = (1.f - fx) * fy,         w11 = fx * fy;
    int o00 = y0 * IMG + x0, o01 = y0 * IMG + x1;
    int o10 = y1 * IMG + x0, o11 = y1 * IMG + x1;
    a0 += w00 * p0[o00] + w01 * p0[o01] + w10 * p0[o10] + w11 * p0[o11];
    a1 += w00 * p1[o00] + w01 * p1[o01] + w10 * p1[o10] + w11 * p1[o11];
    a2 += w00 * p2[o00] + w01 * p2[o01] + w10 * p2[o10] + w11 * p2[o11];
  }
  atomicAdd(&part[h * 3 + 0], a0);
  atomicAdd(&part[h * 3 + 1], a1);
  atomicAdd(&part[h * 3 + 2], a2);
  __syncthreads();

  if (tid < 48) {
    const int hh = tid / 3, c = tid - hh * 3;
    out[256 + (((b * 3 + c) * 16 + hh) * 32) + s] = part[tid] * 0.01f;
  }
}

// ---------------------------------------------------------------------------
extern "C" void kernel_launch(void* const* d_in, const int* in_sizes, int n_in,
                              void* d_out, int out_size, void* d_ws, size_t ws_size,
                              hipStream_t stream) {
  const float* x     = (const float*)d_in[0];
  const float* lprev = (const float*)d_in[1];
  const float* g2d   = (const float*)d_in[2];
  const float* w1    = (const float*)d_in[3];
  const float* b1    = (const float*)d_in[4];
  const float* w2    = (const float*)d_in[5];
  const float* b2    = (const float*)d_in[6];
  const float* f1w   = (const float*)d_in[7];
  const float* f1b   = (const float*)d_in[8];
  const float* f2w   = (const float*)d_in[9];
  const float* f2b   = (const float*)d_in[10];
  float* out = (float*)d_out;

  float* S   = (float*)d_ws;                      // [128][150]
  unsigned int* w1p = (unsigned int*)((char*)d_ws + WS_W1P_OFF);
  ushort4* xi = (ushort4*)((char*)d_ws + WS_XI_OFF);

  const bool fast = (ws_size >= WS_NEED);

  k0w_pack<<<76, 256, 0, stream>>>(w1, w1p, S);   // weights + S zeroing
  k1_conv1<<<dim3(49, NB), 256, 0, stream>>>(x, w1p, b1, S, xi, fast ? 1 : 0);
  if (fast)
    k3_sector<<<dim3(8, NB), 320, 0, stream>>>(
        xi, lprev, g2d, S, w2, b2, f1w, f1b, f2w, f2b, out);
  else
    k3_fallback<<<dim3(32, NB), 320, 0, stream>>>(
        x, lprev, g2d, S, w2, b2, f1w, f1b, f2w, f2b, out);
}

// Round 15
// 127.070 us; speedup vs baseline: 1.2411x; 1.0244x over previous
//
#include <hip/hip_runtime.h>
#include <hip/hip_fp16.h>
#include <math.h>

#define IMG   224
#define PLANE (IMG * IMG)
#define POOL1 110
#define NB    128

// ws layout: S[128*150] f32 | wgt[128*2] f32 | w1p[270] u32 | pad | xi ushort4
#define WS_W1P_OFF  77824ull
#define WS_XI_OFF   81920ull
#define WS_XI_BYTES (128ull * PLANE * 8ull)
#define WS_NEED     (WS_XI_OFF + WS_XI_BYTES + 16ull)  // +16: x1 overread pad

typedef __attribute__((ext_vector_type(2))) _Float16 half2_t;
typedef __attribute__((ext_vector_type(8))) unsigned short ushort8;

// dot2: acc += a.x*b.x + a.y*b.y  (f16 inputs, f32 accumulate)
static __device__ __forceinline__ float fdot2f(unsigned int a, unsigned int b, float c) {
#if __has_builtin(__builtin_amdgcn_fdot2)
  return __builtin_amdgcn_fdot2(__builtin_bit_cast(half2_t, a),
                                __builtin_bit_cast(half2_t, b), c, false);
#else
  float a0 = __half2float(__ushort_as_half((unsigned short)(a & 0xffff)));
  float a1 = __half2float(__ushort_as_half((unsigned short)(a >> 16)));
  float b0 = __half2float(__ushort_as_half((unsigned short)(b & 0xffff)));
  float b1 = __half2float(__ushort_as_half((unsigned short)(b >> 16)));
  return fmaf(a1, b1, fmaf(a0, b0, c));
#endif
}

static __device__ __forceinline__ float h2f(unsigned short u) {
  return __half2float(__ushort_as_half(u));
}

// ---------------------------------------------------------------------------
// k0w: block 0 packs conv1 weights into w1p; blocks 1..75 zero S.
// ---------------------------------------------------------------------------
__global__ __launch_bounds__(256) void k0w_pack(
    const float* __restrict__ w1, unsigned int* __restrict__ w1p,
    float* __restrict__ S)
{
  const int t = threadIdx.x;
  if (blockIdx.x == 0) {
    if (t >= 90) return;
    const int ky = t % 5, r = t / 5, oc = r % 6, c = r / 6;
    const float* w = w1 + ((oc * 3 + c) * 5 + ky) * 5;
    unsigned int* o = w1p + t * 3;
    o[0] = __builtin_bit_cast(unsigned int, __builtin_amdgcn_cvt_pkrtz(w[0], w[1]));
    o[1] = __builtin_bit_cast(unsigned int, __builtin_amdgcn_cvt_pkrtz(w[2], w[3]));
    o[2] = __builtin_bit_cast(unsigned int, w[4]);
  } else {
    S[(blockIdx.x - 1) * 256 + t] = 0.0f;   // 75*256 = 19200 = 128*150
  }
}

// ---------------------------------------------------------------------------
// Kernel 1: conv1(3->6,5x5) + maxpool2x2 + shifted-window sums into S
// + fused xi emission. Channel loop at unroll-1 (R12's full unroll regressed:
// VGPR 32->44, occupancy 63->48%, 90->118 µs — TLP loss beat ILP gain).
// Stable at 88-90 µs / VGPR 32 across R9-R14.
// ---------------------------------------------------------------------------
__global__ __launch_bounds__(256) void k1_conv1(
    const float* __restrict__ x, const unsigned int* __restrict__ w1p,
    const float* __restrict__ b1, float* __restrict__ S,
    ushort4* __restrict__ xi, const int write_xi)
{
  const int tid = threadIdx.x;
  const int tile = blockIdx.x;          // 0..48
  const int b = blockIdx.y;
  const int t_y = tile / 7, t_x = tile % 7;
  const int P0y = t_y * 16, P0x = t_x * 16;
  const int ty = tid >> 4, tx = tid & 15;
  const int py = P0y + ty, px = P0x + tx;
  const bool xedge = (t_x == 0) || (t_x == 6);   // block-uniform

  __shared__ _Float16 in_t[3][36][40];  // fp16 staging
  __shared__ float rp[16][6][5];

  const int by = 2 * P0y, bx = 2 * P0x;
  #pragma unroll
  for (int dr = 0; dr < 3; ++dr) {
    const int row = ty + dr * 16;
    if (dr == 2 && row >= 36) continue;
    const int gy = min(by + row, IMG - 1);
    #pragma unroll
    for (int dc = 0; dc < 3; ++dc) {
      const int col = tx + dc * 16;
      if (dc == 2 && col >= 36) continue;
      const int gx = min(bx + col, IMG - 1);
      const float* src = x + ((size_t)(b * 3) * IMG + gy) * IMG + gx;
      #pragma unroll
      for (int c = 0; c < 3; ++c)
        in_t[c][row][col] = (_Float16)src[c * PLANE];
    }
  }
  __syncthreads();

  float acc[6][4];
  #pragma unroll
  for (int oc = 0; oc < 6; ++oc) {
    float bb = b1[oc];
    acc[oc][0] = bb; acc[oc][1] = bb; acc[oc][2] = bb; acc[oc][3] = bb;
  }
  unsigned int core_r0[3], core_r1[3];

  #pragma unroll 1
  for (int c = 0; c < 3; ++c) {
    const unsigned int* wc = w1p + c * 90;   // [(oc*5+ky)*3 + j]
    #pragma unroll
    for (int i = 0; i < 6; ++i) {
      const unsigned int* rowp =
          (const unsigned int*)&in_t[c][2 * ty + i][2 * tx];
      const unsigned int u0 = rowp[0], u1 = rowp[1], u2 = rowp[2];
      const unsigned int o1 = (u0 >> 16) | (u1 << 16);   // (v1,v2)
      const unsigned int o3 = (u1 >> 16) | (u2 << 16);   // (v3,v4)
      const float f4 = h2f((unsigned short)(u2 & 0xffff));
      const float f5 = h2f((unsigned short)(u2 >> 16));
      if (i == 0) { core_r0[c] = u0; }
      if (i == 1) { core_r1[c] = u0; }
      #pragma unroll
      for (int oc = 0; oc < 6; ++oc) {
        if (i <= 4) {
          const unsigned int* w = wc + (oc * 5 + i) * 3;
          const unsigned int w01 = w[0], w23 = w[1];
          const float w4 = __builtin_bit_cast(float, w[2]);
          acc[oc][0] = fdot2f(u0, w01, acc[oc][0]);
          acc[oc][0] = fdot2f(u1, w23, acc[oc][0]);
          acc[oc][0] = fmaf(f4, w4, acc[oc][0]);
          acc[oc][1] = fdot2f(o1, w01, acc[oc][1]);
          acc[oc][1] = fdot2f(o3, w23, acc[oc][1]);
          acc[oc][1] = fmaf(f5, w4, acc[oc][1]);
        }
        if (i >= 1) {
          const unsigned int* w = wc + (oc * 5 + (i - 1)) * 3;
          const unsigned int w01 = w[0], w23 = w[1];
          const float w4 = __builtin_bit_cast(float, w[2]);
          acc[oc][2] = fdot2f(u0, w01, acc[oc][2]);
          acc[oc][2] = fdot2f(u1, w23, acc[oc][2]);
          acc[oc][2] = fmaf(f4, w4, acc[oc][2]);
          acc[oc][3] = fdot2f(o1, w01, acc[oc][3]);
          acc[oc][3] = fdot2f(o3, w23, acc[oc][3]);
          acc[oc][3] = fmaf(f5, w4, acc[oc][3]);
        }
      }
    }
  }

  if (write_xi) {
    const int gy0 = by + 2 * ty, gx0 = bx + 2 * tx;
    ushort4* dst = xi + (size_t)b * PLANE + (size_t)gy0 * IMG + gx0;
    {
      uint4 pk;
      pk.x = (core_r0[0] & 0xffffu) | (core_r0[1] << 16);
      pk.y = (core_r0[2] & 0xffffu);
      pk.z = (core_r0[0] >> 16) | (core_r0[1] & 0xffff0000u);
      pk.w = (core_r0[2] >> 16);
      *(uint4*)dst = pk;
    }
    {
      uint4 pk;
      pk.x = (core_r1[0] & 0xffffu) | (core_r1[1] << 16);
      pk.y = (core_r1[2] & 0xffffu);
      pk.z = (core_r1[0] >> 16) | (core_r1[1] & 0xffff0000u);
      pk.w = (core_r1[2] >> 16);
      *(uint4*)(dst + IMG) = pk;
    }
  }

  const bool valid = (py < POOL1) && (px < POOL1);
  float z[6];
  #pragma unroll
  for (int oc = 0; oc < 6; ++oc) {
    float m = fmaxf(fmaxf(acc[oc][0], acc[oc][1]),
                    fmaxf(acc[oc][2], acc[oc][3]));
    z[oc] = valid ? m : 0.0f;
  }

  if (xedge) {
    #pragma unroll
    for (int oc = 0; oc < 6; ++oc) {
      #pragma unroll
      for (int kx = 0; kx < 5; ++kx) {
        float vv = (px >= kx && px <= 105 + kx) ? z[oc] : 0.0f;
        vv += __shfl_xor(vv, 1, 16);
        vv += __shfl_xor(vv, 2, 16);
        vv += __shfl_xor(vv, 4, 16);
        vv += __shfl_xor(vv, 8, 16);
        if (tx == 0) rp[ty][oc][kx] = vv;
      }
    }
  } else {
    #pragma unroll
    for (int oc = 0; oc < 6; ++oc) {
      float vv = z[oc];
      vv += __shfl_xor(vv, 1, 16);
      vv += __shfl_xor(vv, 2, 16);
      vv += __shfl_xor(vv, 4, 16);
      vv += __shfl_xor(vv, 8, 16);
      if (tx == 0) rp[ty][oc][0] = vv;
    }
  }
  __syncthreads();

  if (tid < 150) {
    int oc = tid / 25, r = tid % 25, ky = r / 5, kx = r % 5;
    const int kxi = xedge ? kx : 0;
    float s = 0.f;
    #pragma unroll
    for (int t = 0; t < 16; ++t) {
      int gpy = P0y + t;
      if (gpy >= ky && gpy <= 105 + ky) s += rp[t][oc][kxi];
    }
    atomicAdd(&S[b * 150 + tid], s);
  }
}

// ---------------------------------------------------------------------------
// Kernel 2 (parallel, R11-best): one block per batch element, 64 threads.
// Lane t covers i = t, t+64, t+128; butterfly reduce; lane 0 runs fc head.
// (R12/R13's fusion into k3 measured ~3 µs SLOWER: the per-block redundant
// head delayed every k3 block's start more than the saved dispatch.)
// ---------------------------------------------------------------------------
__global__ __launch_bounds__(64) void k2_head(
    const float* __restrict__ S, const float* __restrict__ w2,
    const float* __restrict__ b2, const float* __restrict__ f1w,
    const float* __restrict__ f1b, const float* __restrict__ f2w,
    const float* __restrict__ f2b, float* __restrict__ wgt,
    float* __restrict__ out)
{
  const int b = blockIdx.x;
  const int t = threadIdx.x;

  float acc[16];
  #pragma unroll
  for (int oc = 0; oc < 16; ++oc) acc[oc] = 0.0f;
  #pragma unroll 1
  for (int i = t; i < 150; i += 64) {
    float sv = S[b * 150 + i];
    #pragma unroll
    for (int oc = 0; oc < 16; ++oc)
      acc[oc] = fmaf(w2[oc * 150 + i], sv, acc[oc]);
  }
  #pragma unroll
  for (int d = 1; d < 64; d <<= 1) {
    #pragma unroll
    for (int oc = 0; oc < 16; ++oc)
      acc[oc] += __shfl_xor(acc[oc], d, 64);
  }

  if (t == 0) {
    const float inv = 1.0f / (106.0f * 106.0f);
    float br[16];
    #pragma unroll
    for (int oc = 0; oc < 16; ++oc) br[oc] = b2[oc] + acc[oc] * inv;
    float h[8];
    #pragma unroll
    for (int j = 0; j < 8; ++j) {
      float tt = f1b[j];
      #pragma unroll
      for (int oc = 0; oc < 16; ++oc) tt = fmaf(br[oc], f1w[j * 16 + oc], tt);
      h[j] = fmaxf(tt, 0.0f);
    }
    #pragma unroll
    for (int k = 0; k < 2; ++k) {
      float tt = f2b[k];
      #pragma unroll
      for (int j = 0; j < 8; ++j) tt = fmaf(h[j], f2w[k * 8 + j], tt);
      float w = 2.0f / (1.0f + expf(-tt));
      wgt[2 * b + k] = w;
      out[2 * b + k] = w;
    }
  }
}

// ---------------------------------------------------------------------------
// Kernel 3 (fast): polar-sector gather, 4 sectors per block (grid 8x128),
// paired-pixel 16B bilinear loads from the fp16 interleaved image.
// ---------------------------------------------------------------------------
__global__ __launch_bounds__(320) void k3_sector(
    const ushort4* __restrict__ xi, const float* __restrict__ lprev,
    const float* __restrict__ g2d, const float* __restrict__ wgt,
    float* __restrict__ out)
{
  const int sgrp = blockIdx.x;  // 0..7  -> sectors 4*sgrp .. 4*sgrp+3
  const int b = blockIdx.y;     // 0..127
  const int tid = threadIdx.x;  // 0..319
  const int cc = tid % 10;      // theta col within sector
  const int chunk = tid / 10;   // 0..31 -> rows 5*chunk..5*chunk+4
  const int h = chunk >> 1;     // output radius bin

  __shared__ float part[16 * 3];
  if (tid < 48) part[tid] = 0.0f;

  const float lx = lprev[2 * b],  ly = lprev[2 * b + 1];
  const float wx = wgt[2 * b],    wy = wgt[2 * b + 1];
  const float axx = 112.0f * wx, bxx = fmaf(lx, axx, 111.5f);
  const float ayy = 112.0f * wy, byy = fmaf(ly, ayy, 111.5f);
  const int r0 = chunk * 5;
  const unsigned short* xbs = (const unsigned short*)(xi + (size_t)b * PLANE);
  const float2* gp = (const float2*)g2d;
  __syncthreads();

  #pragma unroll 1
  for (int q = 0; q < 4; ++q) {
    const int s = sgrp * 4 + q;
    const int col = s * 10 + cc;
    float a0 = 0.f, a1 = 0.f, a2 = 0.f;
    #pragma unroll
    for (int j = 0; j < 5; ++j) {
      const float2 g = gp[(r0 + j) * 320 + col];
      float ix = fminf(fmaxf(fmaf(g.x, axx, bxx), 0.0f), 223.0f);
      float iy = fminf(fmaxf(fmaf(g.y, ayy, byy), 0.0f), 223.0f);
      float x0f = floorf(ix), y0f = floorf(iy);
      float fx = ix - x0f, fy = iy - y0f;
      int x0 = (int)x0f, y0 = (int)y0f;
      int y1 = min(y0 + 1, IMG - 1);
      ushort8 t, u;                    // [pix x0: c0 c1 c2 pad | pix x0+1]
      __builtin_memcpy(&t, xbs + 4 * (y0 * IMG + x0), 16);
      __builtin_memcpy(&u, xbs + 4 * (y1 * IMG + x0), 16);
      float w00 = (1.f - fx) * (1.f - fy), w01 = fx * (1.f - fy);
      float w10 = (1.f - fx) * fy,         w11 = fx * fy;
      a0 += w00 * h2f(t[0]) + w01 * h2f(t[4]) + w10 * h2f(u[0]) + w11 * h2f(u[4]);
      a1 += w00 * h2f(t[1]) + w01 * h2f(t[5]) + w10 * h2f(u[1]) + w11 * h2f(u[5]);
      a2 += w00 * h2f(t[2]) + w01 * h2f(t[6]) + w10 * h2f(u[2]) + w11 * h2f(u[6]);
    }
    atomicAdd(&part[h * 3 + 0], a0);
    atomicAdd(&part[h * 3 + 1], a1);
    atomicAdd(&part[h * 3 + 2], a2);
    __syncthreads();
    if (tid < 48) {
      const int hh = tid / 3, c = tid - hh * 3;
      out[256 + (((b * 3 + c) * 16 + hh) * 32) + s] = part[tid] * 0.01f;
      part[tid] = 0.0f;
    }
    __syncthreads();
  }
}

// ---------------------------------------------------------------------------
// Kernel 3 (fallback, f32 planar) — used only if ws_size too small for xi.
// ---------------------------------------------------------------------------
__global__ __launch_bounds__(320) void k3_fallback(
    const float* __restrict__ x, const float* __restrict__ lprev,
    const float* __restrict__ g2d, const float* __restrict__ wgt,
    float* __restrict__ out)
{
  const int s = blockIdx.x;
  const int b = blockIdx.y;
  const int tid = threadIdx.x;
  const int cc = tid % 10;
  const int chunk = tid / 10;
  const int h = chunk >> 1;

  __shared__ float part[16 * 3];
  if (tid < 48) part[tid] = 0.0f;

  const float lx = lprev[2 * b],  ly = lprev[2 * b + 1];
  const float wx = wgt[2 * b],    wy = wgt[2 * b + 1];
  const int col = s * 10 + cc;
  const int r0 = chunk * 5;
  const float* xb = x + (size_t)b * 3 * PLANE;
  const float* p0 = xb;
  const float* p1 = xb + PLANE;
  const float* p2 = xb + 2 * PLANE;
  const float2* gp = (const float2*)g2d;
  __syncthreads();

  float a0 = 0.f, a1 = 0.f, a2 = 0.f;
  #pragma unroll
  for (int j = 0; j < 5; ++j) {
    const int rr = r0 + j;
    const float2 g = gp[rr * 320 + col];
    float gx = (lx + g.x) * wx;
    float gy = (ly + g.y) * wy;
    float ix = ((gx + 1.0f) * 224.0f - 1.0f) * 0.5f;
    float iy = ((gy + 1.0f) * 224.0f - 1.0f) * 0.5f;
    ix = fminf(fmaxf(ix, 0.0f), 223.0f);
    iy = fminf(fmaxf(iy, 0.0f), 223.0f);
    float x0f = floorf(ix), y0f = floorf(iy);
    float fx = ix - x0f, fy = iy - y0f;
    int x0 = (int)x0f, y0 = (int)y0f;
    int x1 = min(x0 + 1, IMG - 1), y1 = min(y0 + 1, IMG - 1);
    float w00 = (1.f - fx) * (1.f - fy), w01 = fx * (1.f - fy);
    float w10 = (1.f - fx) * fy,         w11 = fx * fy;
    int o00 = y0 * IMG + x0, o01 = y0 * IMG + x1;
    int o10 = y1 * IMG + x0, o11 = y1 * IMG + x1;
    a0 += w00 * p0[o00] + w01 * p0[o01] + w10 * p0[o10] + w11 * p0[o11];
    a1 += w00 * p1[o00] + w01 * p1[o01] + w10 * p1[o10] + w11 * p1[o11];
    a2 += w00 * p2[o00] + w01 * p2[o01] + w10 * p2[o10] + w11 * p2[o11];
  }
  atomicAdd(&part[h * 3 + 0], a0);
  atomicAdd(&part[h * 3 + 1], a1);
  atomicAdd(&part[h * 3 + 2], a2);
  __syncthreads();

  if (tid < 48) {
    const int hh = tid / 3, c = tid - hh * 3;
    out[256 + (((b * 3 + c) * 16 + hh) * 32) + s] = part[tid] * 0.01f;
  }
}

// ---------------------------------------------------------------------------
extern "C" void kernel_launch(void* const* d_in, const int* in_sizes, int n_in,
                              void* d_out, int out_size, void* d_ws, size_t ws_size,
                              hipStream_t stream) {
  const float* x     = (const float*)d_in[0];
  const float* lprev = (const float*)d_in[1];
  const float* g2d   = (const float*)d_in[2];
  const float* w1    = (const float*)d_in[3];
  const float* b1    = (const float*)d_in[4];
  const float* w2    = (const float*)d_in[5];
  const float* b2    = (const float*)d_in[6];
  const float* f1w   = (const float*)d_in[7];
  const float* f1b   = (const float*)d_in[8];
  const float* f2w   = (const float*)d_in[9];
  const float* f2b   = (const float*)d_in[10];
  float* out = (float*)d_out;

  float* S   = (float*)d_ws;                      // [128][150]
  float* wgt = S + NB * 150;                      // [128][2]
  unsigned int* w1p = (unsigned int*)((char*)d_ws + WS_W1P_OFF);
  ushort4* xi = (ushort4*)((char*)d_ws + WS_XI_OFF);

  const bool fast = (ws_size >= WS_NEED);

  k0w_pack<<<76, 256, 0, stream>>>(w1, w1p, S);   // weights + S zeroing
  k1_conv1<<<dim3(49, NB), 256, 0, stream>>>(x, w1p, b1, S, xi, fast ? 1 : 0);
  k2_head<<<NB, 64, 0, stream>>>(S, w2, b2, f1w, f1b, f2w, f2b, wgt, out);
  if (fast)
    k3_sector<<<dim3(8, NB), 320, 0, stream>>>(xi, lprev, g2d, wgt, out);
  else
    k3_fallback<<<dim3(32, NB), 320, 0, stream>>>(x, lprev, g2d, wgt, out);
}